// Round 9
// baseline (25118.082 us; speedup 1.0000x reference)
//
#include <hip/hip_runtime.h>
#include <hip/hip_bf16.h>
#include <stdint.h>

// Problem: IN=512, H=2048, OUT=512, T=8192. Gate rows 4H=8192.
// Persistent-RNN, round 9: 128 blocks x 256 threads (4 waves), 1 block/CU.
// Wave q owns 4 h-rows x 4 gates = 16 combos; [W_ih|W_hh] resident in 320
// packed-bf16 VGPRs/lane (256-thread blocks keep the full ~512 VGPR/wave
// budget -- r7's 512-thread attempt was capped at 128 VGPRs and spilled).
// Halves rendezvous participants (512 publisher waves) and device-wide poll
// traffic (~1 MB/sweep) vs r6/r8. Keeps the validated protocol: step-tagged
// u64 {bf16 pair | step} via L3, single-deep dwordx4 sweeps, s_sleep(1)
// throttle after 2nd sweep (r4: unthrottled spin congested L3 -> 57ms
// collapse; r5: single hot gotag line serialized one L3 slice).

// ---------------- helpers ----------------

__device__ __forceinline__ uint32_t packbf(float a, float b) {
    // round-to-nearest-even bf16 pack: a -> low16, b -> high16
    uint32_t ua = __float_as_uint(a);
    uint32_t ub = __float_as_uint(b);
    ua = (ua + 0x7fffu + ((ua >> 16) & 1u)) >> 16;
    ub = (ub + 0x7fffu + ((ub >> 16) & 1u)) >> 16;
    return ua | (ub << 16);
}

__device__ __forceinline__ float dot2bf(uint32_t a, uint32_t b, float c) {
    float d;
    asm("v_dot2_f32_bf16 %0, %1, %2, %3" : "=v"(d) : "v"(a), "v"(b), "v"(c));
    return d;
}

__device__ __forceinline__ float sigm(float x) { return 1.f / (1.f + __expf(-x)); }
__device__ __forceinline__ float tanh_fast(float x) { return 1.f - 2.f / (1.f + __expf(2.f * x)); }

#define ASTORE(p, v) __hip_atomic_store((p), (v), __ATOMIC_RELAXED, __HIP_MEMORY_SCOPE_AGENT)

// Two 16B device-scope loads (sc0 sc1), one waitcnt. Tear-safe: each u64
// carries its own tag in the low 32 bits.
__device__ __forceinline__ void aload_2x4(const unsigned long long* pa,
                                          const unsigned long long* pb,
                                          ulonglong2& ra, ulonglong2& rb) {
    asm volatile(
        "global_load_dwordx4 %0, %2, off sc0 sc1\n\t"
        "global_load_dwordx4 %1, %3, off sc0 sc1\n\t"
        "s_waitcnt vmcnt(0)"
        : "=v"(ra), "=v"(rb)
        : "v"(pa), "v"(pb)
        : "memory");
}

// ---------------- kernel 0: invalidate tags ----------------
__global__ __launch_bounds__(256) void init_hbuf(unsigned long long* hbuf) {
    int i = blockIdx.x * 256 + threadIdx.x;
    if (i < 2048) hbuf[i] = ~0ull;  // tag 0xFFFFFFFF never matches a step index
}

// ---------------- kernel 1: persistent LSTM recurrence ----------------
// Block b owns h rows [16b, 16b+16) = pairs [8b, 8b+8). Wave q owns rows
// {hb+4q .. hb+4q+3} (pairs 8b+2q, 8b+2q+1), all 4 gates: combo c in [0,16),
// gate g=c>>2, row r=c&3, weight row R = g*2048 + hb + 4q + r; 20 bf16-pairs
// per combo -> w[320]. Spin: wave q polls pairs [256q, 256q+256): lane L
// watches 4 contiguous pairs {256q+4L..+3} via 2 dwordx4 (one waitcnt).
__global__ __launch_bounds__(256, 1) void lstm_persist(const float* __restrict__ seq,
                                                       const float* __restrict__ Wih,
                                                       const float* __restrict__ Whh,
                                                       const float* __restrict__ bih,
                                                       const float* __restrict__ bhh,
                                                       const float* __restrict__ h0,
                                                       const float* __restrict__ c0,
                                                       unsigned long long* hbuf,
                                                       float* __restrict__ hf32) {
    const int b = blockIdx.x, tid = threadIdx.x;
    const int q = tid >> 6, lane = tid & 63;
    const int hb = b * 16;
    const int myrow = hb + 4 * q + (lane & 3);  // this lane's gate-math row (replicated x16)

    // ---- preload [W_ih | W_hh] rows: 16 combos x 20 packed pairs ----
    uint32_t w[320];
#pragma unroll
    for (int c = 0; c < 16; c++) {
        const int R = (c >> 2) * 2048 + hb + 4 * q + (c & 3);
        const float2* rih = (const float2*)(Wih + (size_t)R * 512);
        const float2* rhh = (const float2*)(Whh + (size_t)R * 2048);
#pragma unroll
        for (int k = 0; k < 4; k++) {
            float2 v = rih[k * 64 + lane];
            w[c * 20 + k] = packbf(v.x, v.y);
        }
#pragma unroll
        for (int k = 4; k < 20; k++) {
            float2 v = rhh[(k - 4) * 64 + lane];
            w[c * 20 + k] = packbf(v.x, v.y);
        }
    }

    __shared__ uint32_t v_stage[2][1024];  // h_{t-1} pairs, parity double-buffered

    // per-lane bias + c state for row `myrow` (replicated x16)
    const float bi  = bih[myrow] + bhh[myrow];
    const float bf_ = bih[2048 + myrow] + bhh[2048 + myrow];
    const float bg  = bih[4096 + myrow] + bhh[4096 + myrow];
    const float bo  = bih[6144 + myrow] + bhh[6144 + myrow];
    float c_state = c0[myrow];

    // publish h0 pairs with tag 0 (parity 0): block b owns pairs [8b, 8b+8)
    if (q == 0 && lane < 8) {
        float a = h0[hb + 2 * lane], b2 = h0[hb + 2 * lane + 1];
        unsigned long long v = ((unsigned long long)packbf(a, b2) << 32);
        ASTORE(&hbuf[b * 8 + lane], v);
    }

    // prefetch x_0: lane owns x pairs {k*64+lane : k in [0,4)}
    float2 xn[4];
#pragma unroll
    for (int k = 0; k < 4; k++) xn[k] = ((const float2*)seq)[k * 64 + lane];

    int gave_up = 0;

    for (int s = 1; s <= 8192; s++) {
        const int t = s - 1, bs = t & 1;
        const uint32_t want = (uint32_t)t;

        // ---- x-part of dot from registers (independent of h; hides publish latency) ----
        float acc[16];
        {
            uint32_t x0 = packbf(xn[0].x, xn[0].y), x1 = packbf(xn[1].x, xn[1].y);
            uint32_t x2 = packbf(xn[2].x, xn[2].y), x3 = packbf(xn[3].x, xn[3].y);
#pragma unroll
            for (int c = 0; c < 16; c++) {
                float a0 = dot2bf(w[c * 20 + 0], x0, 0.f);
                a0 = dot2bf(w[c * 20 + 1], x1, a0);
                a0 = dot2bf(w[c * 20 + 2], x2, a0);
                acc[c] = dot2bf(w[c * 20 + 3], x3, a0);
            }
        }
        // prefetch x_{t+1}
        if (s < 8192) {
            const float2* xp = (const float2*)(seq + (size_t)s * 512);
#pragma unroll
            for (int k = 0; k < 4; k++) xn[k] = xp[k * 64 + lane];
        }

        // ---- distributed spin: wave q owns pairs [256q, 256q+256), lane: 4 contiguous ----
        {
            const unsigned long long* base = hbuf + (bs << 10) + q * 256 + 4 * lane;
            ulonglong2 ra, rb2;
            if (!gave_up) {
                int tries = 0;
                for (;;) {
                    aload_2x4(base, base + 2, ra, rb2);
                    int ok = ((uint32_t)ra.x == want) & ((uint32_t)ra.y == want) &
                             ((uint32_t)rb2.x == want) & ((uint32_t)rb2.y == want);
                    if (__all(ok)) break;
                    if (++tries > (1 << 17)) { gave_up = 1; break; }  // diagnostic fuse
                    if (tries > 1) __builtin_amdgcn_s_sleep(1);  // throttle after 2nd sweep
                }
            } else {
                aload_2x4(base, base + 2, ra, rb2);
            }
            // payloads -> LDS once (4 contiguous pairs: one b128 store)
            *(uint4*)&v_stage[bs][q * 256 + 4 * lane] =
                make_uint4((uint32_t)(ra.x >> 32), (uint32_t)(ra.y >> 32),
                           (uint32_t)(rb2.x >> 32), (uint32_t)(rb2.y >> 32));
        }
        __syncthreads();  // B1: v_stage[bs] ready (the only barrier per step)

        // ---- h-part of dot: 16 combos x 16 pairs per lane ----
#pragma unroll
        for (int k = 0; k < 16; k++) {
            uint32_t hv = v_stage[bs][k * 64 + lane];
#pragma unroll
            for (int c = 0; c < 16; c++) acc[c] = dot2bf(w[c * 20 + 4 + k], hv, acc[c]);
        }

        // ---- fold 16 accs -> 1 (4 stages) + 2 sum stages; lane L holds combo
        // c(L) = 8*b0 + 4*b1 + 2*b2 + b3 (bi = (L>>i)&1), replicated every 16 lanes ----
#pragma unroll
        for (int j = 0; j < 8; j++) {  // d=1: 16 -> 8
            float lo = acc[j], hi = acc[j + 8];
            float sel = (lane & 1) ? lo : hi;
            float got = __shfl_xor(sel, 1, 64);
            acc[j] = ((lane & 1) ? hi : lo) + got;
        }
#pragma unroll
        for (int j = 0; j < 4; j++) {  // d=2: 8 -> 4
            float lo = acc[j], hi = acc[j + 4];
            float sel = (lane & 2) ? lo : hi;
            float got = __shfl_xor(sel, 2, 64);
            acc[j] = ((lane & 2) ? hi : lo) + got;
        }
#pragma unroll
        for (int j = 0; j < 2; j++) {  // d=4: 4 -> 2
            float lo = acc[j], hi = acc[j + 2];
            float sel = (lane & 4) ? lo : hi;
            float got = __shfl_xor(sel, 4, 64);
            acc[j] = ((lane & 4) ? hi : lo) + got;
        }
        {  // d=8: 2 -> 1
            float lo = acc[0], hi = acc[1];
            float sel = (lane & 8) ? lo : hi;
            float got = __shfl_xor(sel, 8, 64);
            acc[0] = ((lane & 8) ? hi : lo) + got;
        }
        acc[0] += __shfl_xor(acc[0], 16, 64);
        acc[0] += __shfl_xor(acc[0], 32, 64);

        // ---- gate gather: combo c sits on lane rev4(c) within each 16-lane group.
        // For this lane's row r = lane&3: rr = rev4(r) = ((lane&1)<<3)|((lane&2)<<1);
        // i: rr+0, g: rr+1, f: rr+2, o: rr+3 (gate bit g1 -> lane bit 1, g0 -> bit 0 reversed) ----
        const int base16 = lane & 48;
        const int rr = ((lane & 1) << 3) | ((lane & 2) << 1);
        float gi = __shfl(acc[0], base16 + rr, 64);
        float gf = __shfl(acc[0], base16 + rr + 2, 64);
        float gg = __shfl(acc[0], base16 + rr + 1, 64);
        float go = __shfl(acc[0], base16 + rr + 3, 64);
        float i_ = sigm(gi + bi), f_ = sigm(gf + bf_), g_ = tanh_fast(gg + bg), o_ = sigm(go + bo);
        c_state = f_ * c_state + i_ * g_;
        float hval = o_ * tanh_fast(c_state);  // lane holds h[row lane&3] (replicated x16)

        // publish: lanes 0,1 each publish one pair {rows 2p, 2p+1} of this wave
        float ha = __shfl(hval, 2 * (lane & 1), 64);
        float hb2 = __shfl(hval, 2 * (lane & 1) + 1, 64);
        if (lane < 2) {
            unsigned long long v = ((unsigned long long)packbf(ha, hb2) << 32) | (uint32_t)s;
            ASTORE(&hbuf[((s & 1) << 10) + b * 8 + 2 * q + lane], v);
        }
        if (s == 8192 && lane < 4) hf32[hb + 4 * q + lane] = hval;
    }
}

// ---------------- kernel 2: pred = h_last @ W_lin^T + b_lin ----------------
__global__ __launch_bounds__(256) void final_linear(const float* __restrict__ hf,
                                                    const float* __restrict__ Wlin,
                                                    const float* __restrict__ blin,
                                                    float* __restrict__ out) {
    const int row = blockIdx.x * 4 + (threadIdx.x >> 6);
    const int lane = threadIdx.x & 63;
    float acc = 0.f;
#pragma unroll
    for (int it = 0; it < 8; it++) {
        int c = it * 256 + lane * 4;
        float4 wv = *(const float4*)&Wlin[(size_t)row * 2048 + c];
        float4 hv = *(const float4*)&hf[c];
        acc += wv.x * hv.x + wv.y * hv.y + wv.z * hv.z + wv.w * hv.w;
    }
#pragma unroll
    for (int off = 32; off; off >>= 1) acc += __shfl_xor(acc, off, 64);
    if (lane == 0) out[row] = acc + blin[row];
}

// ---------------- launch ----------------
extern "C" void kernel_launch(void* const* d_in, const int* in_sizes, int n_in,
                              void* d_out, int out_size, void* d_ws, size_t ws_size,
                              hipStream_t stream) {
    const float* seq  = (const float*)d_in[0];
    const float* Wih  = (const float*)d_in[1];
    const float* Whh  = (const float*)d_in[2];
    const float* bih  = (const float*)d_in[3];
    const float* bhh  = (const float*)d_in[4];
    const float* h0   = (const float*)d_in[5];
    const float* c0   = (const float*)d_in[6];
    const float* Wlin = (const float*)d_in[7];
    const float* blin = (const float*)d_in[8];
    float* out = (float*)d_out;

    char* ws = (char*)d_ws;
    unsigned long long* hbuf = (unsigned long long*)ws;  // 2*1024*8 = 16 KiB
    float* hf32 = (float*)(ws + 16384);                  // 8 KiB

    init_hbuf<<<8, 256, 0, stream>>>(hbuf);
    lstm_persist<<<128, 256, 0, stream>>>(seq, Wih, Whh, bih, bhh, h0, c0, hbuf, hf32);
    final_linear<<<128, 256, 0, stream>>>(hf32, Wlin, blin, out);
}

// Round 10
// 15944.595 us; speedup vs baseline: 1.5753x; 1.5753x over previous
//
#include <hip/hip_runtime.h>
#include <hip/hip_bf16.h>
#include <stdint.h>

// Problem: IN=512, H=2048, OUT=512, T=8192. Gate rows 4H=8192.
// Persistent-RNN: 256 blocks x 256 threads (4 waves), 1 block/CU, [W_ih|W_hh]
// in VGPRs as bf16 pairs (160 u32/lane). h exchanged device-wide as
// step-tagged u64 ({bf16 pair | step}) relaxed agent-scope atomics via L3.
// Round 10 = r8 (16.78ms champion) + two spin-path fixes:
//   - x_{t+1} prefetch moved AFTER spin exit: r8 issued it before the spin,
//     so the spin's first `s_waitcnt vmcnt(0)` drained the prefetch (~200-400ns)
//     on the detection critical path. Now it drains under barrier + h-dot.
//   - 3 unthrottled sweeps (was 2), s_sleep(1) from the 4th: one fewer sleep
//     quantum in the common detect-on-sweep-2/3 case; burst still ~3x below
//     r4's congestion-collapse regime.
// Register-budget law (r7, r9 post-mortems): arch VGPRs cap at 256/wave
// (8-bit encoding; the ~512 unified budget is VGPR+AGPR, and v_dot2 can't
// read AGPRs). 160 weight regs + ~24 live values fits ONLY with 256-thread
// blocks; 512-thread blocks (r7: capped 128) and 320-reg variants (r9:
// capped 256) both spill and regress. Do not revisit.

// ---------------- helpers ----------------

__device__ __forceinline__ uint32_t packbf(float a, float b) {
    // round-to-nearest-even bf16 pack: a -> low16, b -> high16
    uint32_t ua = __float_as_uint(a);
    uint32_t ub = __float_as_uint(b);
    ua = (ua + 0x7fffu + ((ua >> 16) & 1u)) >> 16;
    ub = (ub + 0x7fffu + ((ub >> 16) & 1u)) >> 16;
    return ua | (ub << 16);
}

__device__ __forceinline__ float dot2bf(uint32_t a, uint32_t b, float c) {
    float d;
    asm("v_dot2_f32_bf16 %0, %1, %2, %3" : "=v"(d) : "v"(a), "v"(b), "v"(c));
    return d;
}

__device__ __forceinline__ float sigm(float x) { return 1.f / (1.f + __expf(-x)); }
__device__ __forceinline__ float tanh_fast(float x) { return 1.f - 2.f / (1.f + __expf(2.f * x)); }

#define ASTORE(p, v) __hip_atomic_store((p), (v), __ATOMIC_RELAXED, __HIP_MEMORY_SCOPE_AGENT)

// Two 16B device-scope loads (bypass L1/L2 via sc0 sc1), one waitcnt.
// Tear-safe: each contained u64 carries its own tag in the low 32 bits.
__device__ __forceinline__ void aload_2x4(const unsigned long long* pa,
                                          const unsigned long long* pb,
                                          ulonglong2& ra, ulonglong2& rb) {
    asm volatile(
        "global_load_dwordx4 %0, %2, off sc0 sc1\n\t"
        "global_load_dwordx4 %1, %3, off sc0 sc1\n\t"
        "s_waitcnt vmcnt(0)"
        : "=v"(ra), "=v"(rb)
        : "v"(pa), "v"(pb)
        : "memory");
}

// ---------------- kernel 0: invalidate tags ----------------
__global__ __launch_bounds__(256) void init_hbuf(unsigned long long* hbuf) {
    int i = blockIdx.x * 256 + threadIdx.x;
    if (i < 2048) hbuf[i] = ~0ull;  // tag 0xFFFFFFFF never matches a step index
}

// ---------------- kernel 1: persistent LSTM recurrence ----------------
// Block b owns h indices [8b, 8b+8). Wave q owns rows {hb+2q, hb+2q+1}, ALL 4
// gates (combo c = gate*2 + rowbit). Weights: 160 packed bf16 VGPRs/lane
// (k<4 = W_ih, else W_hh). Spin: wave q polls pairs [256q,256q+256): lane L
// watches pairs {256q+2L, 256q+2L+1} and {256q+128+2L, +1} via 2 dwordx4.
__global__ __launch_bounds__(256, 1) void lstm_persist(const float* __restrict__ seq,
                                                       const float* __restrict__ Wih,
                                                       const float* __restrict__ Whh,
                                                       const float* __restrict__ bih,
                                                       const float* __restrict__ bhh,
                                                       const float* __restrict__ h0,
                                                       const float* __restrict__ c0,
                                                       unsigned long long* hbuf,
                                                       float* __restrict__ hf32) {
    const int b = blockIdx.x, tid = threadIdx.x;
    const int q = tid >> 6, lane = tid & 63;
    const int hb = b * 8;
    const int rb = (lane >> 2) & 1;       // this lane's row within the wave's pair
    const int myrow = hb + 2 * q + rb;

    // ---- preload [W_ih | W_hh] rows for all 4 gates of rows {2q, 2q+1} ----
    uint32_t w[160];
#pragma unroll
    for (int c = 0; c < 8; c++) {
        const int R = (c >> 1) * 2048 + hb + 2 * q + (c & 1);
        const float2* rih = (const float2*)(Wih + (size_t)R * 512);
        const float2* rhh = (const float2*)(Whh + (size_t)R * 2048);
#pragma unroll
        for (int k = 0; k < 4; k++) {
            float2 v = rih[k * 64 + lane];
            w[c * 20 + k] = packbf(v.x, v.y);
        }
#pragma unroll
        for (int k = 4; k < 20; k++) {
            float2 v = rhh[(k - 4) * 64 + lane];
            w[c * 20 + k] = packbf(v.x, v.y);
        }
    }

    __shared__ uint32_t v_stage[2][1024];  // h_{t-1} pairs, parity double-buffered

    // per-lane (replicated) bias + c state for row `myrow`
    const float bi  = bih[myrow] + bhh[myrow];
    const float bf_ = bih[2048 + myrow] + bhh[2048 + myrow];
    const float bg  = bih[4096 + myrow] + bhh[4096 + myrow];
    const float bo  = bih[6144 + myrow] + bhh[6144 + myrow];
    float c_state = c0[myrow];

    // publish h0 slice with tag 0 (parity 0)
    if (q == 0 && lane < 4) {
        float a = h0[hb + lane * 2], b2 = h0[hb + lane * 2 + 1];
        unsigned long long v = ((unsigned long long)packbf(a, b2) << 32);
        ASTORE(&hbuf[b * 4 + lane], v);
    }

    // prefetch x_0: lane owns x pairs {k*64+lane : k in [0,4)}
    float2 xn[4];
#pragma unroll
    for (int k = 0; k < 4; k++) xn[k] = ((const float2*)seq)[k * 64 + lane];

    int gave_up = 0;

    for (int s = 1; s <= 8192; s++) {
        const int t = s - 1, bs = t & 1;
        const uint32_t want = (uint32_t)t;

        // ---- x-part of dot from registers (independent of h; hides publish latency) ----
        float acc[8];
        {
            uint32_t x0 = packbf(xn[0].x, xn[0].y), x1 = packbf(xn[1].x, xn[1].y);
            uint32_t x2 = packbf(xn[2].x, xn[2].y), x3 = packbf(xn[3].x, xn[3].y);
#pragma unroll
            for (int c = 0; c < 8; c++) {
                float a0 = dot2bf(w[c * 20 + 0], x0, 0.f);
                a0 = dot2bf(w[c * 20 + 1], x1, a0);
                a0 = dot2bf(w[c * 20 + 2], x2, a0);
                acc[c] = dot2bf(w[c * 20 + 3], x3, a0);
            }
        }
        // NOTE: x_{t+1} prefetch deliberately NOT issued here — it would be
        // drained by the spin's first s_waitcnt vmcnt(0) (critical path).

        // ---- distributed spin: wave q owns pairs [256q, 256q+256) ----
        {
            const unsigned long long* base = hbuf + (bs << 10) + q * 256;
            const unsigned long long* pa = base + 2 * lane;        // pairs 2L, 2L+1
            const unsigned long long* pb = base + 128 + 2 * lane;  // pairs 128+2L, +1
            ulonglong2 ra, rb2;
            if (!gave_up) {
                int tries = 0;
                for (;;) {
                    aload_2x4(pa, pb, ra, rb2);
                    int ok = ((uint32_t)ra.x == want) & ((uint32_t)ra.y == want) &
                             ((uint32_t)rb2.x == want) & ((uint32_t)rb2.y == want);
                    if (__all(ok)) break;
                    if (++tries > (1 << 17)) { gave_up = 1; break; }  // diagnostic fuse
                    if (tries > 2) __builtin_amdgcn_s_sleep(1);  // throttle from 4th sweep
                }
            } else {
                aload_2x4(pa, pb, ra, rb2);
            }
            // payload -> LDS once (adjacent pairs: two b64 stores)
            uint2* vsa = (uint2*)&v_stage[bs][q * 256 + 2 * lane];
            uint2* vsb = (uint2*)&v_stage[bs][q * 256 + 128 + 2 * lane];
            *vsa = make_uint2((uint32_t)(ra.x >> 32), (uint32_t)(ra.y >> 32));
            *vsb = make_uint2((uint32_t)(rb2.x >> 32), (uint32_t)(rb2.y >> 32));
        }

        // prefetch x_{t+1}: drains under the barrier + h-dot, off the spin path
        if (s < 8192) {
            const float2* xp = (const float2*)(seq + (size_t)s * 512);
#pragma unroll
            for (int k = 0; k < 4; k++) xn[k] = xp[k * 64 + lane];
        }

        __syncthreads();  // B1: v_stage[bs] ready (the only barrier per step)

        // ---- h-part of dot: 8 combos x 16 pairs per lane ----
#pragma unroll
        for (int k = 0; k < 16; k++) {
            uint32_t hv = v_stage[bs][k * 64 + lane];
#pragma unroll
            for (int c = 0; c < 8; c++) acc[c] = dot2bf(w[c * 20 + 4 + k], hv, acc[c]);
        }

        // ---- fold 8 accs -> 1 (3 stages) + 3 sum stages; lane L holds combo
        // c(L&7) = 4*(L&1) + 2*((L>>1)&1) + ((L>>2)&1), replicated every 8 lanes ----
#pragma unroll
        for (int j = 0; j < 4; j++) {  // d=1: 8 -> 4
            float lo = acc[j], hi = acc[j + 4];
            float sel = (lane & 1) ? lo : hi;
            float got = __shfl_xor(sel, 1, 64);
            acc[j] = ((lane & 1) ? hi : lo) + got;
        }
#pragma unroll
        for (int j = 0; j < 2; j++) {  // d=2: 4 -> 2
            float lo = acc[j], hi = acc[j + 2];
            float sel = (lane & 2) ? lo : hi;
            float got = __shfl_xor(sel, 2, 64);
            acc[j] = ((lane & 2) ? hi : lo) + got;
        }
        {  // d=4: 2 -> 1
            float lo = acc[0], hi = acc[1];
            float sel = (lane & 4) ? lo : hi;
            float got = __shfl_xor(sel, 4, 64);
            acc[0] = ((lane & 4) ? hi : lo) + got;
        }
        acc[0] += __shfl_xor(acc[0], 8, 64);
        acc[0] += __shfl_xor(acc[0], 16, 64);
        acc[0] += __shfl_xor(acc[0], 32, 64);

        // combo layout within each 4-lane group (base = lane&~3):
        // base+0: i(row rb), base+1: g, base+2: f, base+3: o  (rb = (lane>>2)&1)
        const int base = lane & ~3;
        float gi = __shfl(acc[0], base, 64);
        float gg = __shfl(acc[0], base + 1, 64);
        float gf = __shfl(acc[0], base + 2, 64);
        float go = __shfl(acc[0], base + 3, 64);
        float i_ = sigm(gi + bi), f_ = sigm(gf + bf_), g_ = tanh_fast(gg + bg), o_ = sigm(go + bo);
        c_state = f_ * c_state + i_ * g_;
        float hval = o_ * tanh_fast(c_state);  // lanes 0-3: row0, lanes 4-7: row1 (replicated)

        float h1 = __shfl(hval, 4, 64);  // row1's h
        if (lane == 0) {
            unsigned long long v = ((unsigned long long)packbf(hval, h1) << 32) | (uint32_t)s;
            ASTORE(&hbuf[((s & 1) << 10) + b * 4 + q], v);
            if (s == 8192) { hf32[hb + 2 * q] = hval; hf32[hb + 2 * q + 1] = h1; }
        }
    }
}

// ---------------- kernel 2: pred = h_last @ W_lin^T + b_lin ----------------
__global__ __launch_bounds__(256) void final_linear(const float* __restrict__ hf,
                                                    const float* __restrict__ Wlin,
                                                    const float* __restrict__ blin,
                                                    float* __restrict__ out) {
    const int row = blockIdx.x * 4 + (threadIdx.x >> 6);
    const int lane = threadIdx.x & 63;
    float acc = 0.f;
#pragma unroll
    for (int it = 0; it < 8; it++) {
        int c = it * 256 + lane * 4;
        float4 wv = *(const float4*)&Wlin[(size_t)row * 2048 + c];
        float4 hv = *(const float4*)&hf[c];
        acc += wv.x * hv.x + wv.y * hv.y + wv.z * hv.z + wv.w * hv.w;
    }
#pragma unroll
    for (int off = 32; off; off >>= 1) acc += __shfl_xor(acc, off, 64);
    if (lane == 0) out[row] = acc + blin[row];
}

// ---------------- launch ----------------
extern "C" void kernel_launch(void* const* d_in, const int* in_sizes, int n_in,
                              void* d_out, int out_size, void* d_ws, size_t ws_size,
                              hipStream_t stream) {
    const float* seq  = (const float*)d_in[0];
    const float* Wih  = (const float*)d_in[1];
    const float* Whh  = (const float*)d_in[2];
    const float* bih  = (const float*)d_in[3];
    const float* bhh  = (const float*)d_in[4];
    const float* h0   = (const float*)d_in[5];
    const float* c0   = (const float*)d_in[6];
    const float* Wlin = (const float*)d_in[7];
    const float* blin = (const float*)d_in[8];
    float* out = (float*)d_out;

    char* ws = (char*)d_ws;
    unsigned long long* hbuf = (unsigned long long*)ws;  // 2*1024*8 = 16 KiB
    float* hf32 = (float*)(ws + 16384);                  // 8 KiB

    init_hbuf<<<8, 256, 0, stream>>>(hbuf);
    lstm_persist<<<256, 256, 0, stream>>>(seq, Wih, Whh, bih, bhh, h0, c0, hbuf, hf32);
    final_linear<<<128, 256, 0, stream>>>(hf32, Wlin, blin, out);
}